// Round 11
// baseline (687.102 us; speedup 1.0000x reference)
//
#include <hip/hip_runtime.h>
#include <hip/hip_fp16.h>

#define N_NODES 50000
#define N_EDGES 1600000
#define D_IN    128
#define D_HID   50
#define D_OUT   10
#define K_CHEB  5

// bucket sort params: bucket = row >> 10 (49 buckets), block-private strips
#define P1_BLOCKS 256
#define EPB       (N_EDGES / P1_BLOCKS)   // 6250 edges per pass-1 block
#define NBUCK     64                      // padded bucket count (49 used)
#define NB_USED   49
#define BCAP      256                     // strip capacity; avg 128, sd ~11 -> 11 sd

#define WH_ELEMS  (K_CHEB * 64 * D_IN)    // 40960 halfs (W^T, n padded to 64)
#define WH_BLOCKS ((WH_ELEMS + 255) / 256)  // 160

#define VROW      64                      // padded hidden row (halfs) = 128 B
#define VSTRIDE   ((size_t)(N_NODES + 1) * VROW)   // +1 zeroed pad row

typedef _Float16 half8_t __attribute__((ext_vector_type(8)));
typedef float    f32x4_t __attribute__((ext_vector_type(4)));

// Clenshaw in hidden space. Since (T_k(M) g0) W_k = T_k(M)(g0 W_k), project first
// (v_k = g0 @ W_k, one MFMA GEMM), then:
//   b3 = v3 + 2M v4;  b2 = v2 + 2M b3 - v4;  b1 = v1 + 2M b2 - b3;
//   S  = v0 +  M b1 - b2;   out = log_softmax(relu(sdeg*S + bias) @ fc_w + fc_b)
// with (M v)[r] = -dinv2[r] * sum_{c in N(r)} v[c]. SpMM rows are 128 B (64 halfs)
// instead of 256 B -> gather traffic halves; src buffer 6.4 MB ~ XCD L2.
// Zero-degree nodes: dinv=0 -> g0 row 0 -> row = bias path (accepted, P ~ 6e-10).
// R11 fix: vgemm writeback now copies the full 16-half segment per thread
// (two uint4), not 8 halfs — R10 left half of each v row unwritten (absmax 2.6).

// ------- fused prep: pass1 bucket scatter + Wh build + pad-row clears ----
__global__ __launch_bounds__(256) void pass1_kernel(const int* __restrict__ row,
                                                    const int* __restrict__ col,
                                                    unsigned int* __restrict__ store,
                                                    int* __restrict__ bcnt,
                                                    const float* __restrict__ W,
                                                    __half* __restrict__ Wh,
                                                    __half* __restrict__ G0,
                                                    __half* __restrict__ v,
                                                    __half* __restrict__ b1) {
    int tid = threadIdx.x;
    int blk = blockIdx.x;
    if (blk >= P1_BLOCKS) {
        int wb = blk - P1_BLOCKS;
        if (wb < WH_BLOCKS) {            // Wh = fp16 W^T padded: Wh[t][n<64][i<128]
            int idx = wb * 256 + tid;
            if (idx < WH_ELEMS) {
                int i = idx & 127;
                int n = (idx >> 7) & 63;
                int t = idx >> 13;
                float vv = (n < D_HID) ? W[t * D_IN * D_HID + i * D_HID + n] : 0.f;
                Wh[idx] = __float2half(vv);
            }
        } else {                         // zero pad rows: g0 (128h), v4 (64h), b1 (64h)
            if (tid < D_IN) G0[(size_t)N_NODES * D_IN + tid] = __float2half(0.f);
            if (tid < VROW) {
                v[4 * VSTRIDE + (size_t)N_NODES * VROW + tid] = __float2half(0.f);
                b1[(size_t)N_NODES * VROW + tid] = __float2half(0.f);
            }
        }
        return;
    }
    __shared__ int cnt[NBUCK];
    if (tid < NBUCK) cnt[tid] = 0;
    __syncthreads();
    int base = blk * EPB;
    size_t sb = (size_t)blk * (NBUCK * BCAP);
    for (int i = tid; i < EPB; i += 256) {
        int r = row[base + i];
        int c = col[base + i];
        int b = r >> 10;
        int pos = atomicAdd(&cnt[b], 1);
        if (pos >= BCAP) pos = BCAP - 1;   // memory-safety clamp; P(hit) ~ 0
        store[sb + (b << 8) + pos] = ((unsigned int)(r & 1023) << 16) | (unsigned int)c;
    }
    __syncthreads();
    if (tid < NBUCK) bcnt[blk * NBUCK + tid] = cnt[tid];
}

// ---------------- pass 2: per-bucket CSR build (one block per bucket) ----------------
__global__ __launch_bounds__(1024) void pass2_kernel(const unsigned int* __restrict__ store,
                                                     const int* __restrict__ bcnt,
                                                     int* __restrict__ row_start,
                                                     float* __restrict__ dinv,
                                                     float* __restrict__ dinv2,
                                                     float* __restrict__ sdeg,
                                                     int* __restrict__ ewc) {
    __shared__ int hist[1024];
    __shared__ int off[1024];
    __shared__ int fill[1024];
    __shared__ int sb_part[1024];
    __shared__ int pscan[64];
    __shared__ int s_bbase;
    int tid = threadIdx.x;
    int b = blockIdx.x;

    // phase 0: bucket totals + prefix (folded bprefix)
    {
        int bt = tid & 63, seg = tid >> 6;        // 16 segs x 16 strips
        int sum = 0;
        for (int s = seg * 16; s < seg * 16 + 16; ++s) sum += bcnt[s * NBUCK + bt];
        sb_part[tid] = sum;
    }
    __syncthreads();
    if (tid < 64) {
        int tot = 0;
        #pragma unroll
        for (int seg = 0; seg < 16; ++seg) tot += sb_part[seg * 64 + tid];
        pscan[tid] = tot;
    }
    __syncthreads();
    for (int o = 1; o < 64; o <<= 1) {
        int vv = (tid < 64 && tid >= o) ? pscan[tid - o] : 0;
        __syncthreads();
        if (tid < 64) pscan[tid] += vv;
        __syncthreads();
    }
    if (tid == 0) {
        s_bbase = (b == 0) ? 0 : pscan[b - 1];
        if (b == 0) row_start[N_NODES] = pscan[63];
    }
    hist[tid] = 0;
    __syncthreads();
    int bbase_b = s_bbase;

    int strip = tid >> 2;        // 0..255
    int sub   = tid & 3;
    int sn = bcnt[strip * NBUCK + b];
    size_t sb = (size_t)strip * (NBUCK * BCAP) + (b << 8);
    for (int i = sub; i < sn; i += 4)
        atomicAdd(&hist[store[sb + i] >> 16], 1);
    __syncthreads();
    int d = hist[tid];
    off[tid] = d;
    __syncthreads();
    for (int o = 1; o < 1024; o <<= 1) {
        int vv = (tid >= o) ? off[tid - o] : 0;
        __syncthreads();
        off[tid] += vv;
        __syncthreads();
    }
    int excl = off[tid] - d + bbase_b;
    __syncthreads();
    hist[tid] = excl;
    fill[tid] = 0;
    int r = (b << 10) + tid;
    if (r < N_NODES) {
        row_start[r] = excl;
        float fd = (float)d;
        dinv[r]  = d ? rsqrtf(fd)  : 0.f;
        dinv2[r] = d ? (1.f / fd)  : 0.f;
        sdeg[r]  = d ? sqrtf(fd)   : 0.f;
    }
    __syncthreads();
    for (int i = sub; i < sn; i += 4) {
        unsigned int vv = store[sb + i];
        int rl = vv >> 16;
        int c = vv & 0xffff;
        int p = atomicAdd(&fill[rl], 1);
        ewc[hist[rl] + p] = c;
    }
}

// ---------------- g0 = dinv .* x, cast to fp16 ----------------
__global__ void g0_kernel(const float* __restrict__ x, const float* __restrict__ dinv,
                          __half* __restrict__ g0) {
    int i = blockIdx.x * blockDim.x + threadIdx.x;   // one float4 group
    if (i < N_NODES * (D_IN / 4)) {
        int row = i >> 5;                            // D_IN/4 == 32
        float d = dinv[row];
        float4 f = ((const float4*)x)[i];
        __half2 a = __float22half2_rn(make_float2(f.x * d, f.y * d));
        __half2 b = __float22half2_rn(make_float2(f.z * d, f.w * d));
        uint2 u;
        u.x = *(unsigned int*)&a;
        u.y = *(unsigned int*)&b;
        ((uint2*)g0)[i] = u;
    }
}

// ---------------- V = g0 @ [W0..W4]: one MFMA GEMM, output fp16 N x 64 per term ------
// Block: 256 thr = 4 waves, 64 rows; wave = 16 rows. A-frags (g0) loaded once,
// reused across 5 terms. Per term: LDS transpose -> coalesced 32B stores.
__global__ __launch_bounds__(256) void vgemm_kernel(const __half* __restrict__ g0,
                                                    const __half* __restrict__ Wh,
                                                    __half* __restrict__ v) {
    __shared__ __half ts[64 * 72];       // 64 rows x 64 cols, stride 72 halfs (144 B)
    int tid = threadIdx.x;
    int lane = tid & 63;
    int wv = __builtin_amdgcn_readfirstlane(tid >> 6);
    int row0 = blockIdx.x * 64;
    int m = lane & 15;
    int quad = lane >> 4;

    int arow = row0 + wv * 16 + m;
    if (arow > N_NODES) arow = N_NODES;              // zeroed pad row

    half8_t a[4];
    #pragma unroll
    for (int s = 0; s < 4; ++s)
        a[s] = *(const half8_t*)(g0 + (size_t)arow * D_IN + s * 32 + quad * 8);

    for (int t = 0; t < K_CHEB; ++t) {
        f32x4_t acc[4];
        #pragma unroll
        for (int j = 0; j < 4; ++j) acc[j] = (f32x4_t)0.f;
        const __half* Wt = Wh + t * (64 * D_IN);
        #pragma unroll
        for (int s = 0; s < 4; ++s) {
            int ko = s * 32 + quad * 8;
            #pragma unroll
            for (int j = 0; j < 4; ++j) {
                half8_t b = *(const half8_t*)(Wt + (j * 16 + m) * D_IN + ko);
                acc[j] = __builtin_amdgcn_mfma_f32_16x16x32_f16(a[s], b, acc[j], 0, 0, 0);
            }
        }
        // C/D: col = lane&15 (n), row = quad*4+rr (m-dim). Stage tile in LDS.
        #pragma unroll
        for (int j = 0; j < 4; ++j) {
            int c = j * 16 + m;
            #pragma unroll
            for (int rr = 0; rr < 4; ++rr) {
                int lrow = wv * 16 + quad * 4 + rr;
                ts[lrow * 72 + c] = __float2half(acc[j][rr]);
            }
        }
        __syncthreads();
        // coalesced store: 4 threads per row, 16 halfs (32 B, two uint4) each
        {
            int lrow = tid >> 2, part = tid & 3;
            int grow = row0 + lrow;
            if (grow < N_NODES) {
                const uint4* s16 = (const uint4*)(ts + lrow * 72 + part * 16);
                uint4 q0 = s16[0], q1 = s16[1];
                uint4* dst = (uint4*)(v + t * VSTRIDE + (size_t)grow * VROW + part * 16);
                dst[0] = q0;
                dst[1] = q1;
            }
        }
        __syncthreads();
    }
}

// ---------------- Clenshaw SpMM step in hidden space ----------------
// dst[r] = addv[r] + (-alphaM*dinv2[r]) * sum_{c in N(r)} src[c]  - do_sub*subv[r]
// 1 wave/row; 32 lanes cover the 64-half row (half2/lane); 2 edges per gather inst;
// 16 insts (32 edges) in flight; ewc read via wave-uniform s_loads (+32 pad).
__global__ __launch_bounds__(512) void prop_kernel(const int* __restrict__ row_start,
                                                   const int* __restrict__ ewc,
                                                   const float* __restrict__ dinv2,
                                                   const __half* __restrict__ src,
                                                   const __half* __restrict__ addv,
                                                   const __half* __restrict__ subv,
                                                   float alphaM, int do_sub,
                                                   __half* __restrict__ dst) {
    int tid = threadIdx.x;
    int lane = tid & 63;
    int wv = __builtin_amdgcn_readfirstlane(tid >> 6);  // 0..7
    int r = blockIdx.x * 8 + wv;                        // 6250*8 == 50000
    int e0 = row_start[r], e1 = row_start[r + 1];
    float fac = -alphaM * dinv2[r];
    int l = lane & 31;           // half2 lane within row
    int g = lane >> 5;           // edge parity
    const __half2* src2 = (const __half2*)src;
    float ax = 0.f, ay = 0.f;
    for (int e = e0; e < e1; e += 32) {
        int cc[32];
        #pragma unroll
        for (int j = 0; j < 32; ++j) cc[j] = ewc[e + j];   // uniform -> s_load
        #pragma unroll
        for (int i = 0; i < 16; ++i) {
            int c = g ? cc[2 * i + 1] : cc[2 * i];
            int myidx = e + 2 * i + g;
            if (myidx >= e1) c = N_NODES;                  // zeroed pad row
            __half2 vv = src2[(size_t)c * (VROW / 2) + l];
            float2 f = __half22float2(vv);
            ax += f.x;
            ay += f.y;
        }
    }
    ax += __shfl_xor(ax, 32);
    ay += __shfl_xor(ay, 32);
    if (g == 0) {
        size_t o = (size_t)r * (VROW / 2) + l;
        float2 av = __half22float2(((const __half2*)addv)[o]);
        float r0 = av.x + fac * ax;
        float r1 = av.y + fac * ay;
        if (do_sub) {
            float2 sv = __half22float2(((const __half2*)subv)[o]);
            r0 -= sv.x;
            r1 -= sv.y;
        }
        ((__half2*)dst)[o] = __float22half2_rn(make_float2(r0, r1));
    }
}

// ---------------- epilogue: relu(sdeg*S + bias) -> FC -> log_softmax ----------------
__global__ __launch_bounds__(256) void final_kernel(const __half* __restrict__ S,
                                                    const float* __restrict__ sdeg,
                                                    const float* __restrict__ cheb_b,
                                                    const float* __restrict__ fc_w,
                                                    const float* __restrict__ fc_b,
                                                    float* __restrict__ out) {
    int r = blockIdx.x * blockDim.x + threadIdx.x;
    if (r >= N_NODES) return;
    float sc = sdeg[r];
    const __half2* s2 = (const __half2*)(S + (size_t)r * VROW);
    float h[D_HID];
    #pragma unroll
    for (int i = 0; i < D_HID / 2; ++i) {
        float2 f = __half22float2(s2[i]);
        float v0 = sc * f.x + cheb_b[2 * i];
        float v1 = sc * f.y + cheb_b[2 * i + 1];
        h[2 * i]     = v0 > 0.f ? v0 : 0.f;
        h[2 * i + 1] = v1 > 0.f ? v1 : 0.f;
    }
    float lg[D_OUT];
    #pragma unroll
    for (int o = 0; o < D_OUT; ++o) lg[o] = fc_b[o];
    #pragma unroll 2
    for (int i = 0; i < D_HID; ++i) {
        float hv = h[i];
        #pragma unroll
        for (int o = 0; o < D_OUT; ++o) lg[o] += hv * fc_w[i * D_OUT + o];
    }
    float mx = lg[0];
    #pragma unroll
    for (int o = 1; o < D_OUT; ++o) mx = fmaxf(mx, lg[o]);
    float s = 0.f;
    #pragma unroll
    for (int o = 0; o < D_OUT; ++o) s += __expf(lg[o] - mx);
    float ls = __logf(s);
    size_t oo = (size_t)r * D_OUT;
    #pragma unroll
    for (int o = 0; o < D_OUT; ++o) out[oo + o] = lg[o] - mx - ls;
}

extern "C" void kernel_launch(void* const* d_in, const int* in_sizes, int n_in,
                              void* d_out, int out_size, void* d_ws, size_t ws_size,
                              hipStream_t stream) {
    const float* x      = (const float*)d_in[0];
    const int*   edge   = (const int*)d_in[1];
    const float* cheb_w = (const float*)d_in[2];
    const float* cheb_b = (const float*)d_in[3];
    const float* fc_w   = (const float*)d_in[4];
    const float* fc_b   = (const float*)d_in[5];
    float* out = (float*)d_out;

    const int* erow = edge;
    const int* ecol = edge + N_EDGES;

    uintptr_t p = ((uintptr_t)d_ws + 255) & ~(uintptr_t)255;
    auto alloc = [&](size_t bytes) {
        uintptr_t q = p;
        p = (p + bytes + 255) & ~(uintptr_t)255;
        return (void*)q;
    };
    unsigned int* store = (unsigned int*)alloc((size_t)P1_BLOCKS * NBUCK * BCAP * 4);  // 16.8 MB
    int*    bcnt      = (int*)alloc((size_t)P1_BLOCKS * NBUCK * 4);
    int*    row_start = (int*)alloc((size_t)(N_NODES + 1) * 4);
    float*  dinv      = (float*)alloc((size_t)N_NODES * 4);
    float*  dinv2     = (float*)alloc((size_t)N_NODES * 4);
    float*  sdeg      = (float*)alloc((size_t)N_NODES * 4);
    int*    ewc       = (int*)alloc((size_t)(N_EDGES + 32) * 4);   // +32 pad
    __half* Wh        = (__half*)alloc((size_t)WH_ELEMS * 2);      // 80 KB
    __half* g0        = (__half*)alloc((size_t)(N_NODES + 1) * D_IN * 2);  // 12.8 MB
    __half* v         = (__half*)alloc(5 * VSTRIDE * 2);           // v0..v4, 32 MB
    __half* b1        = (__half*)alloc(VSTRIDE * 2);               // 6.4 MB

    // buffer reuse: store (dead after pass2) hosts b3,b2; g0 (dead after vgemm) hosts S
    __half* b3 = (__half*)store;
    __half* b2 = (__half*)store + VSTRIDE;
    __half* S  = g0;

    // fused prep: bucket scatter + Wh + pad clears (g0, v4, b1)
    pass1_kernel<<<P1_BLOCKS + WH_BLOCKS + 1, 256, 0, stream>>>(
        erow, ecol, store, bcnt, cheb_w, Wh, g0, v, b1);
    pass2_kernel<<<NB_USED, 1024, 0, stream>>>(store, bcnt, row_start,
                                               dinv, dinv2, sdeg, ewc);
    // store now dead -> zero b3/b2 pad rows (gather targets)
    hipMemsetAsync(b3 + (size_t)N_NODES * VROW, 0, VROW * 2, stream);
    hipMemsetAsync(b2 + (size_t)N_NODES * VROW, 0, VROW * 2, stream);

    const int C4 = (N_NODES * D_IN / 4 + 255) / 256;
    g0_kernel<<<C4, 256, 0, stream>>>(x, dinv, g0);

    // v_t = g0 @ W_t for t=0..4 (one MFMA GEMM)
    const int GBK = (N_NODES + 63) / 64;
    vgemm_kernel<<<GBK, 256, 0, stream>>>(g0, Wh, v);

    // Clenshaw: 4 SpMMs on 64-half rows
    __half* v0 = v;
    __half* v1 = v + 1 * VSTRIDE;
    __half* v2 = v + 2 * VSTRIDE;
    __half* v3 = v + 3 * VSTRIDE;
    __half* v4 = v + 4 * VSTRIDE;
    const int PB = N_NODES / 8;   // 6250 blocks x 8 waves
    // b3 = v3 + 2M v4
    prop_kernel<<<PB, 512, 0, stream>>>(row_start, ewc, dinv2, v4, v3, v3, 2.f, 0, b3);
    // b2 = v2 + 2M b3 - v4
    prop_kernel<<<PB, 512, 0, stream>>>(row_start, ewc, dinv2, b3, v2, v4, 2.f, 1, b2);
    // b1 = v1 + 2M b2 - b3
    prop_kernel<<<PB, 512, 0, stream>>>(row_start, ewc, dinv2, b2, v1, b3, 2.f, 1, b1);
    // S = v0 + M b1 - b2   (S aliases g0; g0 dead after vgemm)
    prop_kernel<<<PB, 512, 0, stream>>>(row_start, ewc, dinv2, b1, v0, b2, 1.f, 1, S);

    // out = log_softmax(relu(sdeg*S + bias) @ fc_w + fc_b)
    final_kernel<<<(N_NODES + 255) / 256, 256, 0, stream>>>(S, sdeg, cheb_b,
                                                            fc_w, fc_b, out);
}

// Round 12
// 316.667 us; speedup vs baseline: 2.1698x; 2.1698x over previous
//
#include <hip/hip_runtime.h>
#include <hip/hip_fp16.h>

#define N_NODES 50000
#define N_EDGES 1600000
#define D_IN    128
#define D_HID   50
#define D_OUT   10
#define K_CHEB  5

// bucket sort params: bucket = row >> 10 (49 buckets), block-private strips
#define P1_BLOCKS 256
#define EPB       (N_EDGES / P1_BLOCKS)   // 6250 edges per pass-1 block
#define NBUCK     64                      // padded bucket count (49 used)
#define NB_USED   49
#define BCAP      256                     // strip capacity; avg 128, sd ~11 -> 11 sd

#define WH_ELEMS  (K_CHEB * 64 * D_IN)    // 40960 halfs (W^T, n padded to 64)
#define WH_BLOCKS ((WH_ELEMS + 255) / 256)  // 160

#define VROW      64                      // padded hidden row (halfs) = 128 B
#define VSTRIDE   ((size_t)(N_NODES + 1) * VROW)   // +1 zeroed pad row

typedef _Float16 half8_t __attribute__((ext_vector_type(8)));
typedef float    f32x4_t __attribute__((ext_vector_type(4)));

// Clenshaw in hidden space. Since (T_k(M) g0) W_k = T_k(M)(g0 W_k), project first
// (v_k = g0 @ W_k, one MFMA GEMM), then:
//   b3 = v3 + 2M v4;  b2 = v2 + 2M b3 - v4;  b1 = v1 + 2M b2 - b3;
//   S  = v0 +  M b1 - b2;   out = log_softmax(relu(sdeg*S + bias) @ fc_w + fc_b)
// with (M v)[r] = -dinv2[r] * sum_{c in N(r)} v[c]. SpMM rows are 128 B (64 halfs).
// Zero-degree nodes: dinv=0 -> g0 row 0 -> row = bias path (accepted, P ~ 6e-10).
// R12 fix: prop's edge indices are consumed immediately (no cc[32] staging array) —
// R11's array spilled to scratch: 566 MB/dispatch of scratch write traffic.

// ------- fused prep: pass1 bucket scatter + Wh build + pad-row clears ----
__global__ __launch_bounds__(256) void pass1_kernel(const int* __restrict__ row,
                                                    const int* __restrict__ col,
                                                    unsigned int* __restrict__ store,
                                                    int* __restrict__ bcnt,
                                                    const float* __restrict__ W,
                                                    __half* __restrict__ Wh,
                                                    __half* __restrict__ G0,
                                                    __half* __restrict__ v,
                                                    __half* __restrict__ b1) {
    int tid = threadIdx.x;
    int blk = blockIdx.x;
    if (blk >= P1_BLOCKS) {
        int wb = blk - P1_BLOCKS;
        if (wb < WH_BLOCKS) {            // Wh = fp16 W^T padded: Wh[t][n<64][i<128]
            int idx = wb * 256 + tid;
            if (idx < WH_ELEMS) {
                int i = idx & 127;
                int n = (idx >> 7) & 63;
                int t = idx >> 13;
                float vv = (n < D_HID) ? W[t * D_IN * D_HID + i * D_HID + n] : 0.f;
                Wh[idx] = __float2half(vv);
            }
        } else {                         // zero pad rows: g0 (128h), v4 (64h), b1 (64h)
            if (tid < D_IN) G0[(size_t)N_NODES * D_IN + tid] = __float2half(0.f);
            if (tid < VROW) {
                v[4 * VSTRIDE + (size_t)N_NODES * VROW + tid] = __float2half(0.f);
                b1[(size_t)N_NODES * VROW + tid] = __float2half(0.f);
            }
        }
        return;
    }
    __shared__ int cnt[NBUCK];
    if (tid < NBUCK) cnt[tid] = 0;
    __syncthreads();
    int base = blk * EPB;
    size_t sb = (size_t)blk * (NBUCK * BCAP);
    for (int i = tid; i < EPB; i += 256) {
        int r = row[base + i];
        int c = col[base + i];
        int b = r >> 10;
        int pos = atomicAdd(&cnt[b], 1);
        if (pos >= BCAP) pos = BCAP - 1;   // memory-safety clamp; P(hit) ~ 0
        store[sb + (b << 8) + pos] = ((unsigned int)(r & 1023) << 16) | (unsigned int)c;
    }
    __syncthreads();
    if (tid < NBUCK) bcnt[blk * NBUCK + tid] = cnt[tid];
}

// ---------------- pass 2: per-bucket CSR build (one block per bucket) ----------------
__global__ __launch_bounds__(1024) void pass2_kernel(const unsigned int* __restrict__ store,
                                                     const int* __restrict__ bcnt,
                                                     int* __restrict__ row_start,
                                                     float* __restrict__ dinv,
                                                     float* __restrict__ dinv2,
                                                     float* __restrict__ sdeg,
                                                     int* __restrict__ ewc) {
    __shared__ int hist[1024];
    __shared__ int off[1024];
    __shared__ int fill[1024];
    __shared__ int sb_part[1024];
    __shared__ int pscan[64];
    __shared__ int s_bbase;
    int tid = threadIdx.x;
    int b = blockIdx.x;

    // phase 0: bucket totals + prefix (folded bprefix)
    {
        int bt = tid & 63, seg = tid >> 6;        // 16 segs x 16 strips
        int sum = 0;
        for (int s = seg * 16; s < seg * 16 + 16; ++s) sum += bcnt[s * NBUCK + bt];
        sb_part[tid] = sum;
    }
    __syncthreads();
    if (tid < 64) {
        int tot = 0;
        #pragma unroll
        for (int seg = 0; seg < 16; ++seg) tot += sb_part[seg * 64 + tid];
        pscan[tid] = tot;
    }
    __syncthreads();
    for (int o = 1; o < 64; o <<= 1) {
        int vv = (tid < 64 && tid >= o) ? pscan[tid - o] : 0;
        __syncthreads();
        if (tid < 64) pscan[tid] += vv;
        __syncthreads();
    }
    if (tid == 0) {
        s_bbase = (b == 0) ? 0 : pscan[b - 1];
        if (b == 0) row_start[N_NODES] = pscan[63];
    }
    hist[tid] = 0;
    __syncthreads();
    int bbase_b = s_bbase;

    int strip = tid >> 2;        // 0..255
    int sub   = tid & 3;
    int sn = bcnt[strip * NBUCK + b];
    size_t sb = (size_t)strip * (NBUCK * BCAP) + (b << 8);
    for (int i = sub; i < sn; i += 4)
        atomicAdd(&hist[store[sb + i] >> 16], 1);
    __syncthreads();
    int d = hist[tid];
    off[tid] = d;
    __syncthreads();
    for (int o = 1; o < 1024; o <<= 1) {
        int vv = (tid >= o) ? off[tid - o] : 0;
        __syncthreads();
        off[tid] += vv;
        __syncthreads();
    }
    int excl = off[tid] - d + bbase_b;
    __syncthreads();
    hist[tid] = excl;
    fill[tid] = 0;
    int r = (b << 10) + tid;
    if (r < N_NODES) {
        row_start[r] = excl;
        float fd = (float)d;
        dinv[r]  = d ? rsqrtf(fd)  : 0.f;
        dinv2[r] = d ? (1.f / fd)  : 0.f;
        sdeg[r]  = d ? sqrtf(fd)   : 0.f;
    }
    __syncthreads();
    for (int i = sub; i < sn; i += 4) {
        unsigned int vv = store[sb + i];
        int rl = vv >> 16;
        int c = vv & 0xffff;
        int p = atomicAdd(&fill[rl], 1);
        ewc[hist[rl] + p] = c;
    }
}

// ---------------- g0 = dinv .* x, cast to fp16 ----------------
__global__ void g0_kernel(const float* __restrict__ x, const float* __restrict__ dinv,
                          __half* __restrict__ g0) {
    int i = blockIdx.x * blockDim.x + threadIdx.x;   // one float4 group
    if (i < N_NODES * (D_IN / 4)) {
        int row = i >> 5;                            // D_IN/4 == 32
        float d = dinv[row];
        float4 f = ((const float4*)x)[i];
        __half2 a = __float22half2_rn(make_float2(f.x * d, f.y * d));
        __half2 b = __float22half2_rn(make_float2(f.z * d, f.w * d));
        uint2 u;
        u.x = *(unsigned int*)&a;
        u.y = *(unsigned int*)&b;
        ((uint2*)g0)[i] = u;
    }
}

// ---------------- V = g0 @ [W0..W4]: one MFMA GEMM, output fp16 N x 64 per term ------
// Block: 256 thr = 4 waves, 64 rows; wave = 16 rows. A-frags (g0) loaded once,
// reused across 5 terms. Per term: LDS transpose -> coalesced 32B stores.
__global__ __launch_bounds__(256) void vgemm_kernel(const __half* __restrict__ g0,
                                                    const __half* __restrict__ Wh,
                                                    __half* __restrict__ v) {
    __shared__ __half ts[64 * 72];       // 64 rows x 64 cols, stride 72 halfs (144 B)
    int tid = threadIdx.x;
    int lane = tid & 63;
    int wv = __builtin_amdgcn_readfirstlane(tid >> 6);
    int row0 = blockIdx.x * 64;
    int m = lane & 15;
    int quad = lane >> 4;

    int arow = row0 + wv * 16 + m;
    if (arow > N_NODES) arow = N_NODES;              // zeroed pad row

    half8_t a[4];
    #pragma unroll
    for (int s = 0; s < 4; ++s)
        a[s] = *(const half8_t*)(g0 + (size_t)arow * D_IN + s * 32 + quad * 8);

    for (int t = 0; t < K_CHEB; ++t) {
        f32x4_t acc[4];
        #pragma unroll
        for (int j = 0; j < 4; ++j) acc[j] = (f32x4_t)0.f;
        const __half* Wt = Wh + t * (64 * D_IN);
        #pragma unroll
        for (int s = 0; s < 4; ++s) {
            int ko = s * 32 + quad * 8;
            #pragma unroll
            for (int j = 0; j < 4; ++j) {
                half8_t b = *(const half8_t*)(Wt + (j * 16 + m) * D_IN + ko);
                acc[j] = __builtin_amdgcn_mfma_f32_16x16x32_f16(a[s], b, acc[j], 0, 0, 0);
            }
        }
        // C/D: col = lane&15 (n), row = quad*4+rr (m-dim). Stage tile in LDS.
        #pragma unroll
        for (int j = 0; j < 4; ++j) {
            int c = j * 16 + m;
            #pragma unroll
            for (int rr = 0; rr < 4; ++rr) {
                int lrow = wv * 16 + quad * 4 + rr;
                ts[lrow * 72 + c] = __float2half(acc[j][rr]);
            }
        }
        __syncthreads();
        // coalesced store: 4 threads per row, 16 halfs (32 B, two uint4) each
        {
            int lrow = tid >> 2, part = tid & 3;
            int grow = row0 + lrow;
            if (grow < N_NODES) {
                const uint4* s16 = (const uint4*)(ts + lrow * 72 + part * 16);
                uint4 q0 = s16[0], q1 = s16[1];
                uint4* dst = (uint4*)(v + t * VSTRIDE + (size_t)grow * VROW + part * 16);
                dst[0] = q0;
                dst[1] = q1;
            }
        }
        __syncthreads();
    }
}

// ---------------- Clenshaw SpMM step in hidden space ----------------
// dst[r] = addv[r] + (-alphaM*dinv2[r]) * sum_{c in N(r)} src[c]  - do_sub*subv[r]
// 1 wave/row; 32 lanes cover the 64-half row (half2/lane); 2 edges per gather inst
// (lane>>5 picks the edge); 8 gathers in flight; edge indices consumed immediately
// (no staging array -> no scratch). ewc over-allocated by +32 ints (masked).
__global__ __launch_bounds__(512) void prop_kernel(const int* __restrict__ row_start,
                                                   const int* __restrict__ ewc,
                                                   const float* __restrict__ dinv2,
                                                   const __half* __restrict__ src,
                                                   const __half* __restrict__ addv,
                                                   const __half* __restrict__ subv,
                                                   float alphaM, int do_sub,
                                                   __half* __restrict__ dst) {
    int tid = threadIdx.x;
    int lane = tid & 63;
    int wv = __builtin_amdgcn_readfirstlane(tid >> 6);  // 0..7
    int r = blockIdx.x * 8 + wv;                        // 6250*8 == 50000
    int e0 = row_start[r], e1 = row_start[r + 1];
    float fac = -alphaM * dinv2[r];
    int l = lane & 31;           // half2 lane within row
    int g = lane >> 5;           // edge parity
    const __half2* src2 = (const __half2*)src;
    float ax = 0.f, ay = 0.f;
    for (int e = e0; e < e1; e += 16) {
        #pragma unroll
        for (int i = 0; i < 8; ++i) {
            int ca = ewc[e + 2 * i];          // uniform -> s_load, consumed now
            int cb = ewc[e + 2 * i + 1];
            int c = g ? cb : ca;
            if (e + 2 * i + g >= e1) c = N_NODES;   // zeroed pad row
            float2 f = __half22float2(src2[(size_t)c * (VROW / 2) + l]);
            ax += f.x;
            ay += f.y;
        }
    }
    ax += __shfl_xor(ax, 32);
    ay += __shfl_xor(ay, 32);
    if (g == 0) {
        size_t o = (size_t)r * (VROW / 2) + l;
        float2 av = __half22float2(((const __half2*)addv)[o]);
        float r0 = av.x + fac * ax;
        float r1 = av.y + fac * ay;
        if (do_sub) {
            float2 sv = __half22float2(((const __half2*)subv)[o]);
            r0 -= sv.x;
            r1 -= sv.y;
        }
        ((__half2*)dst)[o] = __float22half2_rn(make_float2(r0, r1));
    }
}

// ---------------- epilogue: relu(sdeg*S + bias) -> FC -> log_softmax ----------------
__global__ __launch_bounds__(256) void final_kernel(const __half* __restrict__ S,
                                                    const float* __restrict__ sdeg,
                                                    const float* __restrict__ cheb_b,
                                                    const float* __restrict__ fc_w,
                                                    const float* __restrict__ fc_b,
                                                    float* __restrict__ out) {
    int r = blockIdx.x * blockDim.x + threadIdx.x;
    if (r >= N_NODES) return;
    float sc = sdeg[r];
    const __half2* s2 = (const __half2*)(S + (size_t)r * VROW);
    float h[D_HID];
    #pragma unroll
    for (int i = 0; i < D_HID / 2; ++i) {
        float2 f = __half22float2(s2[i]);
        float v0 = sc * f.x + cheb_b[2 * i];
        float v1 = sc * f.y + cheb_b[2 * i + 1];
        h[2 * i]     = v0 > 0.f ? v0 : 0.f;
        h[2 * i + 1] = v1 > 0.f ? v1 : 0.f;
    }
    float lg[D_OUT];
    #pragma unroll
    for (int o = 0; o < D_OUT; ++o) lg[o] = fc_b[o];
    #pragma unroll 2
    for (int i = 0; i < D_HID; ++i) {
        float hv = h[i];
        #pragma unroll
        for (int o = 0; o < D_OUT; ++o) lg[o] += hv * fc_w[i * D_OUT + o];
    }
    float mx = lg[0];
    #pragma unroll
    for (int o = 1; o < D_OUT; ++o) mx = fmaxf(mx, lg[o]);
    float s = 0.f;
    #pragma unroll
    for (int o = 0; o < D_OUT; ++o) s += __expf(lg[o] - mx);
    float ls = __logf(s);
    size_t oo = (size_t)r * D_OUT;
    #pragma unroll
    for (int o = 0; o < D_OUT; ++o) out[oo + o] = lg[o] - mx - ls;
}

extern "C" void kernel_launch(void* const* d_in, const int* in_sizes, int n_in,
                              void* d_out, int out_size, void* d_ws, size_t ws_size,
                              hipStream_t stream) {
    const float* x      = (const float*)d_in[0];
    const int*   edge   = (const int*)d_in[1];
    const float* cheb_w = (const float*)d_in[2];
    const float* cheb_b = (const float*)d_in[3];
    const float* fc_w   = (const float*)d_in[4];
    const float* fc_b   = (const float*)d_in[5];
    float* out = (float*)d_out;

    const int* erow = edge;
    const int* ecol = edge + N_EDGES;

    uintptr_t p = ((uintptr_t)d_ws + 255) & ~(uintptr_t)255;
    auto alloc = [&](size_t bytes) {
        uintptr_t q = p;
        p = (p + bytes + 255) & ~(uintptr_t)255;
        return (void*)q;
    };
    unsigned int* store = (unsigned int*)alloc((size_t)P1_BLOCKS * NBUCK * BCAP * 4);  // 16.8 MB
    int*    bcnt      = (int*)alloc((size_t)P1_BLOCKS * NBUCK * 4);
    int*    row_start = (int*)alloc((size_t)(N_NODES + 1) * 4);
    float*  dinv      = (float*)alloc((size_t)N_NODES * 4);
    float*  dinv2     = (float*)alloc((size_t)N_NODES * 4);
    float*  sdeg      = (float*)alloc((size_t)N_NODES * 4);
    int*    ewc       = (int*)alloc((size_t)(N_EDGES + 32) * 4);   // +32 pad
    __half* Wh        = (__half*)alloc((size_t)WH_ELEMS * 2);      // 80 KB
    __half* g0        = (__half*)alloc((size_t)(N_NODES + 1) * D_IN * 2);  // 12.8 MB
    __half* v         = (__half*)alloc(5 * VSTRIDE * 2);           // v0..v4, 32 MB
    __half* b1        = (__half*)alloc(VSTRIDE * 2);               // 6.4 MB

    // buffer reuse: store (dead after pass2) hosts b3,b2; g0 (dead after vgemm) hosts S
    __half* b3 = (__half*)store;
    __half* b2 = (__half*)store + VSTRIDE;
    __half* S  = g0;

    // fused prep: bucket scatter + Wh + pad clears (g0, v4, b1)
    pass1_kernel<<<P1_BLOCKS + WH_BLOCKS + 1, 256, 0, stream>>>(
        erow, ecol, store, bcnt, cheb_w, Wh, g0, v, b1);
    pass2_kernel<<<NB_USED, 1024, 0, stream>>>(store, bcnt, row_start,
                                               dinv, dinv2, sdeg, ewc);
    // store now dead -> zero b3/b2 pad rows (gather targets)
    hipMemsetAsync(b3 + (size_t)N_NODES * VROW, 0, VROW * 2, stream);
    hipMemsetAsync(b2 + (size_t)N_NODES * VROW, 0, VROW * 2, stream);

    const int C4 = (N_NODES * D_IN / 4 + 255) / 256;
    g0_kernel<<<C4, 256, 0, stream>>>(x, dinv, g0);

    // v_t = g0 @ W_t for t=0..4 (one MFMA GEMM)
    const int GBK = (N_NODES + 63) / 64;
    vgemm_kernel<<<GBK, 256, 0, stream>>>(g0, Wh, v);

    // Clenshaw: 4 SpMMs on 64-half rows
    __half* v0 = v;
    __half* v1 = v + 1 * VSTRIDE;
    __half* v2 = v + 2 * VSTRIDE;
    __half* v3 = v + 3 * VSTRIDE;
    __half* v4 = v + 4 * VSTRIDE;
    const int PB = N_NODES / 8;   // 6250 blocks x 8 waves
    // b3 = v3 + 2M v4
    prop_kernel<<<PB, 512, 0, stream>>>(row_start, ewc, dinv2, v4, v3, v3, 2.f, 0, b3);
    // b2 = v2 + 2M b3 - v4
    prop_kernel<<<PB, 512, 0, stream>>>(row_start, ewc, dinv2, b3, v2, v4, 2.f, 1, b2);
    // b1 = v1 + 2M b2 - b3
    prop_kernel<<<PB, 512, 0, stream>>>(row_start, ewc, dinv2, b2, v1, b3, 2.f, 1, b1);
    // S = v0 + M b1 - b2   (S aliases g0; g0 dead after vgemm)
    prop_kernel<<<PB, 512, 0, stream>>>(row_start, ewc, dinv2, b1, v0, b2, 1.f, 1, S);

    // out = log_softmax(relu(sdeg*S + bias) @ fc_w + fc_b)
    final_kernel<<<(N_NODES + 255) / 256, 256, 0, stream>>>(S, sdeg, cheb_b,
                                                            fc_w, fc_b, out);
}